// Round 2
// baseline (143.909 us; speedup 1.0000x reference)
//
#include <hip/hip_runtime.h>

// Problem constants
#define HW      1024   // H*W = 32*32 = BN channel count
#define BC      4096   // B*C = 16*256 = elements per BN channel
#define NLAYERS 30
#define TPB     512    // ode threads/block: 8 elems/lane -> 32 waves/CU budget

// ---------------------------------------------------------------------------
// Tiled fp32 transpose, 64x64 tile, 256 threads, float4 on BOTH sides.
// LDS row stride 65 -> scalar LDS accesses land 2 lanes/bank (free on CDNA4).
// ---------------------------------------------------------------------------
__global__ __launch_bounds__(256) void transpose64(const float* __restrict__ src,
                                                   float* __restrict__ dst,
                                                   int R, int C) {
    __shared__ float tile[64][65];
    const int rb = blockIdx.y * 64;
    const int cb = blockIdx.x * 64;
    const int r  = threadIdx.x >> 4;         // 0..15
    const int c4 = (threadIdx.x & 15) * 4;   // 0,4,...,60
#pragma unroll
    for (int i = 0; i < 4; ++i) {
        const int row = r + 16 * i;
        const float4 v = *(const float4*)(src + (size_t)(rb + row) * C + cb + c4);
        tile[row][c4 + 0] = v.x; tile[row][c4 + 1] = v.y;
        tile[row][c4 + 2] = v.z; tile[row][c4 + 3] = v.w;
    }
    __syncthreads();
#pragma unroll
    for (int i = 0; i < 4; ++i) {
        const int a = r + 16 * i;            // dst row offset == src col
        float4 w;
        w.x = tile[c4 + 0][a]; w.y = tile[c4 + 1][a];
        w.z = tile[c4 + 2][a]; w.w = tile[c4 + 3][a];
        *(float4*)(dst + (size_t)(cb + a) * R + rb + c4) = w;
    }
}

// ---------------------------------------------------------------------------
// 30-layer ODE. One block per BN channel p; 512 threads x 8 values in
// registers = the 4096 (b,c) values of that channel. Per layer:
//   z = fma(m[c], x1, y); block reduce (sum,sumsq); BN+ReLU6 (med3); Euler.
// Reduction: 6-step wave butterfly (ds_swizzle) + 8-wave LDS combine,
// double-buffered so there is exactly ONE barrier per layer.
// ---------------------------------------------------------------------------
__global__ __launch_bounds__(TPB, 8) void ode_main(const float* __restrict__ xT,
                                                   const float* __restrict__ delta_t,
                                                   const float* __restrict__ matrices,
                                                   const float* __restrict__ gamma,
                                                   const float* __restrict__ beta,
                                                   float* __restrict__ yT) {
    const int p = blockIdx.x;
    const int t = threadIdx.x;               // 0..511
    const float* xrow = xT + (size_t)p * BC;

    // element e(j,i) = j*2048 + 4t + i ; c = e % 256 = (4t+i) & 255 (2048%256==0)
    float x1[8], y[8];
#pragma unroll
    for (int j = 0; j < 2; ++j) {
        const float4 v = *(const float4*)(xrow + j * 2048 + 4 * t);
        x1[j * 4 + 0] = v.x; x1[j * 4 + 1] = v.y;
        x1[j * 4 + 2] = v.z; x1[j * 4 + 3] = v.w;
    }
#pragma unroll
    for (int k = 0; k < 8; ++k) y[k] = x1[k];

    const float gp   = gamma[p];
    const float bp   = beta[p];
    const int   wid  = t >> 6;               // 0..7
    const int   lane = t & 63;
    const int   moff = (4 * t) & 255;

    __shared__ float red[2][16];             // [parity][wave*2 + {sum,sumsq}]

    for (int l = 0; l < NLAYERS; ++l) {
        const float4 mv = *(const float4*)(matrices + l * 256 + moff);
        const float mm[4] = {mv.x, mv.y, mv.z, mv.w};
        const float dtl = __builtin_amdgcn_fmed3f(delta_t[l], 0.0f, 6.0f);

        float z[8];
        float s = 0.0f, s2 = 0.0f;
#pragma unroll
        for (int j = 0; j < 2; ++j) {
#pragma unroll
            for (int i = 0; i < 4; ++i) {
                const float zz = fmaf(mm[i], x1[j * 4 + i], y[j * 4 + i]);
                z[j * 4 + i] = zz;
                s += zz;
                s2 = fmaf(zz, zz, s2);
            }
        }
        // 64-lane butterfly: every lane ends with the wave total
#pragma unroll
        for (int mask = 1; mask < 64; mask <<= 1) {
            s  += __shfl_xor(s,  mask, 64);
            s2 += __shfl_xor(s2, mask, 64);
        }
        const int par = l & 1;
        if (lane == 0) { red[par][wid * 2] = s; red[par][wid * 2 + 1] = s2; }
        __syncthreads();
        float S = 0.0f, S2 = 0.0f;
#pragma unroll
        for (int w = 0; w < 8; ++w) {        // broadcast reads: conflict-free
            S  += red[par][w * 2];
            S2 += red[par][w * 2 + 1];
        }

        const float mean = S * (1.0f / 4096.0f);
        const float var  = fmaf(-mean, mean, S2 * (1.0f / 4096.0f));
        const float rstd = rsqrtf(var + 1e-5f);
        const float g    = gp * rstd;            // fold gamma into scale
        const float bb   = fmaf(-mean, g, bp);   // fold mean into bias
        const float omdt = 1.0f - dtl;
#pragma unroll
        for (int k = 0; k < 8; ++k) {
            const float a = __builtin_amdgcn_fmed3f(fmaf(z[k], g, bb), 0.0f, 6.0f);
            y[k] = fmaf(dtl, a, omdt * y[k]);    // y += dt*(-y + relu6(bn))
        }
    }

    float* yrow = yT + (size_t)p * BC;
#pragma unroll
    for (int j = 0; j < 2; ++j) {
        float4 w;
        w.x = y[j * 4 + 0] + x1[j * 4 + 0];
        w.y = y[j * 4 + 1] + x1[j * 4 + 1];
        w.z = y[j * 4 + 2] + x1[j * 4 + 2];
        w.w = y[j * 4 + 3] + x1[j * 4 + 3];
        *(float4*)(yrow + j * 2048 + 4 * t) = w;
    }
}

// ---------------------------------------------------------------------------
// K1 x -> xT (scratch = d_out, fully overwritten by K3),
// K2 30-layer ODE xT -> yT (scratch = d_ws),
// K3 yT -> d_out (final layout == x layout).
// ---------------------------------------------------------------------------
extern "C" void kernel_launch(void* const* d_in, const int* in_sizes, int n_in,
                              void* d_out, int out_size, void* d_ws, size_t ws_size,
                              hipStream_t stream) {
    const float* x        = (const float*)d_in[0];   // [16,256,32,32]
    const float* delta_t  = (const float*)d_in[1];   // [30,1]
    const float* matrices = (const float*)d_in[2];   // [30,1,1,16,16]
    const float* gamma    = (const float*)d_in[3];   // [1024]
    const float* beta     = (const float*)d_in[4];   // [1024]
    float* out = (float*)d_out;

    float* xT = out;            // 16 MB scratch; overwritten by K3
    float* yT = (float*)d_ws;   // 16 MB scratch

    // x viewed as [BC=4096][HW=1024] -> xT [1024][4096]
    transpose64<<<dim3(HW / 64, BC / 64), dim3(256), 0, stream>>>(x, xT, BC, HW);
    ode_main<<<dim3(HW), dim3(TPB), 0, stream>>>(xT, delta_t, matrices, gamma, beta, yT);
    // yT [1024][4096] -> out [4096][1024]
    transpose64<<<dim3(BC / 64, HW / 64), dim3(256), 0, stream>>>(yT, out, HW, BC);
}

// Round 3
// 133.538 us; speedup vs baseline: 1.0777x; 1.0777x over previous
//
#include <hip/hip_runtime.h>

// Problem constants
#define HW      1024   // H*W = 32*32 = BN channel count (spatial positions)
#define BC      4096   // B*C = 16*256 = elements per BN channel
#define NLAYERS 30
#define TPB     256    // 16 elems/thread: best measured ops/elem (R1 vs R2)

// ---------------------------------------------------------------------------
// Single fused kernel. One block per BN channel p. Thread t owns elements
// e = t + 256k (k=0..15)  =>  c = e mod 256 = t, so each thread uses ONE
// scalar m per layer (staged in LDS). Gather/scatter x/out columns directly
// (4B/lane, stride 4KB) — unique traffic is 16 MB, L3-resident, lines fully
// consumed across 16 blocks; beats two transpose kernels + launch gaps.
// Per layer: z = fma(m, x1, y); 64-lane butterfly + 4-wave LDS combine
// (double-buffered parity -> exactly ONE __syncthreads per layer);
// BN + ReLU6 (v_med3); Euler step.
// ---------------------------------------------------------------------------
__global__ __launch_bounds__(TPB) void ode_fused(const float* __restrict__ x,
                                                 const float* __restrict__ delta_t,
                                                 const float* __restrict__ matrices,
                                                 const float* __restrict__ gamma,
                                                 const float* __restrict__ beta,
                                                 float* __restrict__ out) {
    const int p = blockIdx.x;       // spatial position = BN channel
    const int t = threadIdx.x;      // 0..255 ; also c = t

    __shared__ float smat[NLAYERS * 256];  // 30 KB: per-layer m[c]
    __shared__ float sdt[NLAYERS];         // relu6(delta_t)
    __shared__ float red[2][8];            // [parity][wave*2 + {sum,sumsq}]

    // Stage matrices (coalesced) and clipped delta_t into LDS.
#pragma unroll
    for (int i = 0; i < NLAYERS; ++i)
        smat[i * 256 + t] = matrices[i * 256 + t];
    if (t < NLAYERS)
        sdt[t] = __builtin_amdgcn_fmed3f(delta_t[t], 0.0f, 6.0f);

    // Gather column p: 16 independent 4B loads, stride 4 KB (L2/L3-served).
    float x1[16], y[16];
#pragma unroll
    for (int k = 0; k < 16; ++k)
        x1[k] = x[(size_t)(t + 256 * k) * HW + p];
#pragma unroll
    for (int k = 0; k < 16; ++k) y[k] = x1[k];

    const float gp   = gamma[p];
    const float bp   = beta[p];
    const int   wid  = t >> 6;
    const int   lane = t & 63;

    __syncthreads();  // staging done

    for (int l = 0; l < NLAYERS; ++l) {
        const float m   = smat[l * 256 + t];   // stride-1: 2 lanes/bank, free
        const float dtl = sdt[l];              // broadcast

        float z[16];
        float s = 0.0f, s2 = 0.0f;
#pragma unroll
        for (int k = 0; k < 16; ++k) {
            const float zz = fmaf(m, x1[k], y[k]);
            z[k] = zz;
            s += zz;
            s2 = fmaf(zz, zz, s2);
        }
        // 64-lane butterfly: every lane ends with the wave totals
#pragma unroll
        for (int mask = 1; mask < 64; mask <<= 1) {
            s  += __shfl_xor(s,  mask, 64);
            s2 += __shfl_xor(s2, mask, 64);
        }
        const int par = l & 1;
        if (lane == 0) { red[par][wid * 2] = s; red[par][wid * 2 + 1] = s2; }
        __syncthreads();
        const float S  = red[par][0] + red[par][2] + red[par][4] + red[par][6];
        const float S2 = red[par][1] + red[par][3] + red[par][5] + red[par][7];

        const float mean = S * (1.0f / 4096.0f);
        const float var  = fmaf(-mean, mean, S2 * (1.0f / 4096.0f));
        const float rstd = rsqrtf(var + 1e-5f);
        const float g    = gp * rstd;            // fold gamma into scale
        const float bb   = fmaf(-mean, g, bp);   // fold mean into bias
        const float omdt = 1.0f - dtl;
#pragma unroll
        for (int k = 0; k < 16; ++k) {
            const float a = __builtin_amdgcn_fmed3f(fmaf(z[k], g, bb), 0.0f, 6.0f);
            y[k] = fmaf(dtl, a, omdt * y[k]);    // y += dt*(-y + relu6(bn))
        }
    }

    // Scatter out = y + x1 back in x's layout (stores merge to lines in L2).
#pragma unroll
    for (int k = 0; k < 16; ++k)
        out[(size_t)(t + 256 * k) * HW + p] = y[k] + x1[k];
}

extern "C" void kernel_launch(void* const* d_in, const int* in_sizes, int n_in,
                              void* d_out, int out_size, void* d_ws, size_t ws_size,
                              hipStream_t stream) {
    const float* x        = (const float*)d_in[0];   // [16,256,32,32]
    const float* delta_t  = (const float*)d_in[1];   // [30,1]
    const float* matrices = (const float*)d_in[2];   // [30,1,1,16,16]
    const float* gamma    = (const float*)d_in[3];   // [1024]
    const float* beta     = (const float*)d_in[4];   // [1024]
    float* out = (float*)d_out;

    ode_fused<<<dim3(HW), dim3(TPB), 0, stream>>>(x, delta_t, matrices, gamma, beta, out);
}

// Round 4
// 121.736 us; speedup vs baseline: 1.1821x; 1.0969x over previous
//
#include <hip/hip_runtime.h>

typedef float v2f __attribute__((ext_vector_type(2)));

// Problem constants
#define HW      1024   // H*W = BN channel count (spatial positions)
#define BC      4096   // B*C = elements per BN channel
#define NLAYERS 30
#define TPB     256    // 16 elems/thread (best ops/elem, R1 vs R2)

// ---------------------------------------------------------------------------
// Single fused kernel. One block per BN channel p; thread t owns elements
// e = t + 256k (k=0..15), so c = e mod 256 = t -> ONE scalar m per layer.
//
// XCD swizzle: p = (bid%8)*128 + bid/8. Round-robin blockIdx->XCD puts each
// contiguous 128-wide p-range on ONE XCD, so every 64B line of x/out (16
// consecutive p) is fetched/written by a single XCD L2 -> gather/scatter
// traffic collapses to the unique 16+16 MB (R3 measured 74+137 MB without).
//
// Elementwise math in packed fp32 (v_pk_fma_f32 et al. via float2 vectors):
// halves VALU issue of the 8-op/elem body. (sum,sumsq) ride one v2f through
// the 64-lane butterfly; 8-wave combine via tiny double-buffered LDS ->
// exactly ONE __syncthreads per layer.
// ---------------------------------------------------------------------------
__global__ __launch_bounds__(TPB) void ode_fused(const float* __restrict__ x,
                                                 const float* __restrict__ delta_t,
                                                 const float* __restrict__ matrices,
                                                 const float* __restrict__ gamma,
                                                 const float* __restrict__ beta,
                                                 float* __restrict__ out) {
    const int bid = blockIdx.x;
    const int p   = ((bid & 7) << 7) | (bid >> 3);   // XCD-contiguous channel
    const int t   = threadIdx.x;                     // 0..255 ; c = t

    __shared__ float smat[NLAYERS * 256];  // 30 KB per-layer m[c]
    __shared__ float sdt[NLAYERS];
    __shared__ v2f   red[2][4];            // [parity][wave] = (sum, sumsq)

#pragma unroll
    for (int i = 0; i < NLAYERS; ++i)
        smat[i * 256 + t] = matrices[i * 256 + t];
    if (t < NLAYERS)
        sdt[t] = __builtin_amdgcn_fmed3f(delta_t[t], 0.0f, 6.0f);

    // Gather column p. Pair k holds e = t+256*(2k) and t+256*(2k+1).
    v2f x1[8], y[8];
#pragma unroll
    for (int k = 0; k < 8; ++k) {
        x1[k].x = x[(size_t)(t + 512 * k) * HW + p];
        x1[k].y = x[(size_t)(t + 512 * k + 256) * HW + p];
        y[k] = x1[k];
    }

    const float gp   = gamma[p];
    const float bp   = beta[p];
    const int   wid  = t >> 6;
    const int   lane = t & 63;

    __syncthreads();  // staging done

    for (int l = 0; l < NLAYERS; ++l) {
        const float m   = smat[l * 256 + t];
        const float dtl = sdt[l];
        const v2f m2 = {m, m};

        v2f z[8];
        v2f sA = {0.f, 0.f}, sB = {0.f, 0.f};   // two chains: shorter dep path
        v2f qA = {0.f, 0.f}, qB = {0.f, 0.f};
#pragma unroll
        for (int k = 0; k < 8; k += 2) {
            z[k]     = __builtin_elementwise_fma(m2, x1[k], y[k]);
            z[k + 1] = __builtin_elementwise_fma(m2, x1[k + 1], y[k + 1]);
            sA += z[k];
            sB += z[k + 1];
            qA = __builtin_elementwise_fma(z[k], z[k], qA);
            qB = __builtin_elementwise_fma(z[k + 1], z[k + 1], qB);
        }
        const v2f sv = sA + sB;
        const v2f qv = qA + qB;
        v2f pr; pr.x = sv.x + sv.y; pr.y = qv.x + qv.y;   // (sum, sumsq)

        // 64-lane butterfly on the packed pair
#pragma unroll
        for (int mask = 1; mask < 64; mask <<= 1) {
            v2f o;
            o.x = __shfl_xor(pr.x, mask, 64);
            o.y = __shfl_xor(pr.y, mask, 64);
            pr += o;
        }
        const int par = l & 1;
        if (lane == 0) red[par][wid] = pr;
        __syncthreads();
        const v2f tot = red[par][0] + red[par][1] + red[par][2] + red[par][3];

        const float mean = tot.x * (1.0f / 4096.0f);
        const float var  = fmaf(-mean, mean, tot.y * (1.0f / 4096.0f));
        const float rstd = rsqrtf(var + 1e-5f);
        const float g    = gp * rstd;            // fold gamma into scale
        const float bb   = fmaf(-mean, g, bp);   // fold mean into bias
        const v2f g2  = {g, g},   b2 = {bb, bb};
        const v2f dt2 = {dtl, dtl};
        const v2f z2  = {0.f, 0.f}, s6 = {6.f, 6.f};
#pragma unroll
        for (int k = 0; k < 8; ++k) {
            v2f a = __builtin_elementwise_fma(z[k], g2, b2);
            a = __builtin_elementwise_max(a, z2);
            a = __builtin_elementwise_min(a, s6);
            y[k] = __builtin_elementwise_fma(dt2, a - y[k], y[k]);  // Euler
        }
    }

    // Scatter out = y + x1 back in x's layout; lines merge in the XCD's L2.
#pragma unroll
    for (int k = 0; k < 8; ++k) {
        out[(size_t)(t + 512 * k) * HW + p]       = y[k].x + x1[k].x;
        out[(size_t)(t + 512 * k + 256) * HW + p] = y[k].y + x1[k].y;
    }
}

extern "C" void kernel_launch(void* const* d_in, const int* in_sizes, int n_in,
                              void* d_out, int out_size, void* d_ws, size_t ws_size,
                              hipStream_t stream) {
    const float* x        = (const float*)d_in[0];   // [16,256,32,32]
    const float* delta_t  = (const float*)d_in[1];   // [30,1]
    const float* matrices = (const float*)d_in[2];   // [30,1,1,16,16]
    const float* gamma    = (const float*)d_in[3];   // [1024]
    const float* beta     = (const float*)d_in[4];   // [1024]
    float* out = (float*)d_out;

    ode_fused<<<dim3(HW), dim3(TPB), 0, stream>>>(x, delta_t, matrices, gamma, beta, out);
}

// Round 5
// 116.093 us; speedup vs baseline: 1.2396x; 1.0486x over previous
//
#include <hip/hip_runtime.h>

typedef float v2f __attribute__((ext_vector_type(2)));

// Problem constants
#define HW      1024   // H*W = BN channel count (spatial positions)
#define NLAYERS 30
#define TPB     256    // 16 elems/thread

// ---------------------------------------------------------------------------
// DPP-based wave64 sum (classic gfx9 sequence, pure VALU — no LDS pipe):
//   row_shr:1,2,4,8  -> lane 15 of each row-of-16 holds its row sum
//   row_bcast15 (rows 1,3) -> lane31 = rows0+1, lane63 = rows2+3
//   row_bcast31 (rows 2,3) -> lane63 = total
// Chain ~6 VALU adds (~50 cyc) vs ~400 cyc for a ds_bpermute butterfly.
// ---------------------------------------------------------------------------
template <int CTRL, int RMASK>
__device__ __forceinline__ float dpp_add(float x) {
    int t = __builtin_amdgcn_update_dpp(0, __builtin_bit_cast(int, x),
                                        CTRL, RMASK, 0xf, true);
    return x + __builtin_bit_cast(float, t);
}
__device__ __forceinline__ float wave_sum64(float x) {
    x = dpp_add<0x111, 0xf>(x);   // row_shr:1
    x = dpp_add<0x112, 0xf>(x);   // row_shr:2
    x = dpp_add<0x114, 0xf>(x);   // row_shr:4
    x = dpp_add<0x118, 0xf>(x);   // row_shr:8
    x = dpp_add<0x142, 0xa>(x);   // row_bcast15 -> rows 1,3
    x = dpp_add<0x143, 0xc>(x);   // row_bcast31 -> rows 2,3
    return x;                     // lane 63 = wave total
}

// ---------------------------------------------------------------------------
// Fused 30-layer ODE. One block per BN channel p (XCD-swizzled); thread t
// owns elements e = t + 256k -> c = t, ONE scalar m per layer.
// Per layer: z = fma(m,x1,y); y *= (1-dt) [off-chain]; DPP wave sums;
// lane63 -> LDS; ONE barrier; 32B broadcast read-back; BN+ReLU6; Euler fma.
// Next layer's m is prefetched before the barrier (lgkm drains with it).
// ---------------------------------------------------------------------------
__global__ __launch_bounds__(TPB) void ode_fused(const float* __restrict__ x,
                                                 const float* __restrict__ delta_t,
                                                 const float* __restrict__ matrices,
                                                 const float* __restrict__ gamma,
                                                 const float* __restrict__ beta,
                                                 float* __restrict__ out) {
    const int bid = blockIdx.x;
    const int p   = ((bid & 7) << 7) | (bid >> 3);   // XCD-contiguous channel
    const int t   = threadIdx.x;                     // 0..255 ; c = t

    __shared__ float smat[(NLAYERS + 1) * 256];      // +1 pad row for prefetch
    __shared__ float sdt[NLAYERS];
    __shared__ __align__(16) v2f red[2][4];          // [parity][wave]=(s,s2)

#pragma unroll
    for (int i = 0; i < NLAYERS; ++i)
        smat[i * 256 + t] = matrices[i * 256 + t];
    if (t < NLAYERS)
        sdt[t] = __builtin_amdgcn_fmed3f(delta_t[t], 0.0f, 6.0f);

    // Gather column p (XCD swizzle keeps each 64B line on one XCD's L2).
    v2f x1[8], y[8];
#pragma unroll
    for (int k = 0; k < 8; ++k) {
        x1[k].x = x[(size_t)(t + 512 * k) * HW + p];
        x1[k].y = x[(size_t)(t + 512 * k + 256) * HW + p];
        y[k] = x1[k];
    }

    const float gp   = gamma[p];
    const float bp   = beta[p];
    const int   wid  = t >> 6;
    const int   lane = t & 63;

    __syncthreads();  // staging + gather visible
    float m_cur = smat[t];

    for (int l = 0; l < NLAYERS; ++l) {
        const float dtl = sdt[l];
        const v2f m2    = {m_cur, m_cur};
        const v2f dt2   = {dtl, dtl};
        const v2f om2   = {1.0f - dtl, 1.0f - dtl};

        v2f z[8];
        v2f sA = {0.f, 0.f}, sB = {0.f, 0.f};
        v2f qA = {0.f, 0.f}, qB = {0.f, 0.f};
#pragma unroll
        for (int k = 0; k < 8; k += 2) {
            z[k]     = __builtin_elementwise_fma(m2, x1[k], y[k]);
            z[k + 1] = __builtin_elementwise_fma(m2, x1[k + 1], y[k + 1]);
            sA += z[k];
            sB += z[k + 1];
            qA = __builtin_elementwise_fma(z[k], z[k], qA);
            qB = __builtin_elementwise_fma(z[k + 1], z[k + 1], qB);
        }
        // Off-critical-path: pre-scale y by (1-dt) while the reduction runs.
#pragma unroll
        for (int k = 0; k < 8; ++k) y[k] *= om2;

        const v2f sv = sA + sB;
        const v2f qv = qA + qB;
        float s = wave_sum64(sv.x + sv.y);   // two independent DPP chains
        float q = wave_sum64(qv.x + qv.y);

        const int par = l & 1;
        if (lane == 63) { v2f w; w.x = s; w.y = q; red[par][wid] = w; }
        m_cur = smat[(l + 1) * 256 + t];     // prefetch; drains with barrier
        __syncthreads();

        const float4 r0 = *(const float4*)&red[par][0];  // s0,q0,s1,q1
        const float4 r1 = *(const float4*)&red[par][2];  // s2,q2,s3,q3
        const float S  = (r0.x + r0.z) + (r1.x + r1.z);
        const float S2 = (r0.y + r0.w) + (r1.y + r1.w);

        const float mean = S * (1.0f / 4096.0f);
        const float var  = fmaf(-mean, mean, S2 * (1.0f / 4096.0f));
        const float rstd = rsqrtf(var + 1e-5f);
        const float g    = gp * rstd;            // fold gamma into scale
        const float bb   = fmaf(-mean, g, bp);   // fold mean into bias
        const v2f g2 = {g, g}, b2 = {bb, bb};
        const v2f z0 = {0.f, 0.f}, s6 = {6.f, 6.f};
#pragma unroll
        for (int k = 0; k < 8; ++k) {
            v2f a = __builtin_elementwise_fma(z[k], g2, b2);
            a = __builtin_elementwise_max(a, z0);
            a = __builtin_elementwise_min(a, s6);
            y[k] = __builtin_elementwise_fma(dt2, a, y[k]);  // y=(1-dt)y + dt*a
        }
    }

    // Scatter out = y + x1; lines merge in the owning XCD's L2.
#pragma unroll
    for (int k = 0; k < 8; ++k) {
        out[(size_t)(t + 512 * k) * HW + p]       = y[k].x + x1[k].x;
        out[(size_t)(t + 512 * k + 256) * HW + p] = y[k].y + x1[k].y;
    }
}

extern "C" void kernel_launch(void* const* d_in, const int* in_sizes, int n_in,
                              void* d_out, int out_size, void* d_ws, size_t ws_size,
                              hipStream_t stream) {
    const float* x        = (const float*)d_in[0];   // [16,256,32,32]
    const float* delta_t  = (const float*)d_in[1];   // [30,1]
    const float* matrices = (const float*)d_in[2];   // [30,1,1,16,16]
    const float* gamma    = (const float*)d_in[3];   // [1024]
    const float* beta     = (const float*)d_in[4];   // [1024]
    float* out = (float*)d_out;

    ode_fused<<<dim3(HW), dim3(TPB), 0, stream>>>(x, delta_t, matrices, gamma, beta, out);
}